// Round 1
// baseline (224.577 us; speedup 1.0000x reference)
//
#include <hip/hip_runtime.h>
#include <math.h>

#define SEQ   2048
#define DM    1024
#define NHEAD 16
#define HD    64
#define NTOK  4096
#define EPS   1e-5f
#define SCALE_C 0.18033688f  // 0.125 * log2(e): folded into Q projection

typedef __attribute__((ext_vector_type(8))) short v8s;
typedef __attribute__((ext_vector_type(4))) float v4f;
typedef unsigned short ushort_t;

#define GLOAD16(g, l) __builtin_amdgcn_global_load_lds( \
    (const __attribute__((address_space(1))) unsigned int*)(g), \
    (__attribute__((address_space(3))) unsigned int*)(l), 16, 0, 0)

__device__ __forceinline__ unsigned short f2bf(float f) {
  union { float f; unsigned u; } v; v.f = f;
  unsigned r = v.u + 0x7FFFu + ((v.u >> 16) & 1u);
  return (unsigned short)(r >> 16);
}

// pack two fp32 -> bf16x2 dword (round-half-up): 2 adds + 1 v_perm
__device__ __forceinline__ unsigned pack2_bf16(float a, float b) {
  union { float f; unsigned u; } ua, ub;
  ua.f = a; ub.f = b;
  return __builtin_amdgcn_perm(ub.u + 0x8000u, ua.u + 0x8000u, 0x07060302u);
}

// ---------------- LayerNorm -> bf16 ----------------
__global__ __launch_bounds__(256) void ln_kernel(
    const float* __restrict__ x, const float* __restrict__ g,
    const float* __restrict__ be, ushort_t* __restrict__ y) {
  const int row = blockIdx.x;
  const int t = threadIdx.x;
  const float4 v = ((const float4*)(x + (size_t)row * DM))[t];
  float s  = v.x + v.y + v.z + v.w;
  float ss = v.x*v.x + v.y*v.y + v.z*v.z + v.w*v.w;
  #pragma unroll
  for (int off = 32; off > 0; off >>= 1) {
    s  += __shfl_down(s,  off, 64);
    ss += __shfl_down(ss, off, 64);
  }
  __shared__ float red[8];
  __shared__ float mu_s, rs_s;
  const int wid = t >> 6, lane = t & 63;
  if (lane == 0) { red[wid] = s; red[4 + wid] = ss; }
  __syncthreads();
  if (t == 0) {
    const float S  = red[0] + red[1] + red[2] + red[3];
    const float SS = red[4] + red[5] + red[6] + red[7];
    const float mu  = S * (1.0f / DM);
    const float var = SS * (1.0f / DM) - mu * mu;
    mu_s = mu; rs_s = rsqrtf(var + EPS);
  }
  __syncthreads();
  const float mu = mu_s, r = rs_s;
  const float4 gv = ((const float4*)g)[t];
  const float4 bv = ((const float4*)be)[t];
  ushort4 o;
  o.x = f2bf((v.x - mu) * r * gv.x + bv.x);
  o.y = f2bf((v.y - mu) * r * gv.y + bv.y);
  o.z = f2bf((v.z - mu) * r * gv.z + bv.z);
  o.w = f2bf((v.w - mu) * r * gv.w + bv.w);
  *(ushort4*)(y + (size_t)row * DM + t * 4) = o;
}

// ---------------- W[k][n] fp32 -> WT[n][k] bf16 ----------------
__global__ __launch_bounds__(256) void wt_kernel(
    const float* __restrict__ w0, const float* __restrict__ w1,
    const float* __restrict__ w2, const float* __restrict__ w3,
    ushort_t* __restrict__ o0, ushort_t* __restrict__ o1,
    ushort_t* __restrict__ o2, ushort_t* __restrict__ o3) {
  const int z = blockIdx.z;
  const float* w = (z==0) ? w0 : (z==1) ? w1 : (z==2) ? w2 : w3;
  ushort_t* o    = (z==0) ? o0 : (z==1) ? o1 : (z==2) ? o2 : o3;
  __shared__ float tile[64][65];
  const int t = threadIdx.x;
  const int n0 = blockIdx.x * 64, k0 = blockIdx.y * 64;
  const int r = t >> 4, c4 = (t & 15) * 4;
  #pragma unroll
  for (int i = 0; i < 4; ++i) {
    const float4 v = *(const float4*)(w + (size_t)(k0 + r + i*16) * DM + n0 + c4);
    tile[r + i*16][c4 + 0] = v.x;
    tile[r + i*16][c4 + 1] = v.y;
    tile[r + i*16][c4 + 2] = v.z;
    tile[r + i*16][c4 + 3] = v.w;
  }
  __syncthreads();
  #pragma unroll
  for (int i = 0; i < 4; ++i) {
    const int n = r + i*16;
    ushort4 o4;
    o4.x = f2bf(tile[c4 + 0][n]);
    o4.y = f2bf(tile[c4 + 1][n]);
    o4.z = f2bf(tile[c4 + 2][n]);
    o4.w = f2bf(tile[c4 + 3][n]);
    *(ushort4*)(o + (size_t)(n0 + n) * DM + k0 + c4) = o4;
  }
}

// ---------------- bf16 MFMA GEMM mainloop (2-phase double-buffered) ----------------
// T3 "minimum 2-phase" recipe: stage tile k+1 into the other LDS buffer right
// after the barrier that publishes tile k, then compute tile k. One barrier
// per K-step; global_load_lds latency hides under the 16 MFMAs.
__device__ __forceinline__ void gemm_main(ushort_t (*lsa)[128*32], ushort_t (*lsb)[128*32],
    const ushort_t* A, const ushort_t* WT, int m0, int n0, v4f acc[4][4]) {
  const int tid = threadIdx.x;
  const int wid = tid >> 6, lane = tid & 63;
  const int mh = (wid & 1) << 6, nh = (wid >> 1) << 6;
  const int r16 = lane & 15, quad = lane >> 4;
  const int srow = lane >> 2, sch = lane & 3;
  // prologue: stage k0=0 into buffer 0
  #pragma unroll
  for (int j = 0; j < 2; ++j) {
    const int o = wid * 2 + j;
    GLOAD16(A  + (size_t)(m0 + o*16 + srow) * DM + sch*8, lsa[0] + o*512);
    GLOAD16(WT + (size_t)(n0 + o*16 + srow) * DM + sch*8, lsb[0] + o*512);
  }
  int cur = 0;
  for (int k0 = 0; k0 < DM; k0 += 32) {
    __syncthreads();  // drains vmcnt: buf[cur] staged; buf[cur^1] free to overwrite
    if (k0 + 32 < DM) {
      #pragma unroll
      for (int j = 0; j < 2; ++j) {
        const int o = wid * 2 + j;
        GLOAD16(A  + (size_t)(m0 + o*16 + srow) * DM + k0 + 32 + sch*8, lsa[cur^1] + o*512);
        GLOAD16(WT + (size_t)(n0 + o*16 + srow) * DM + k0 + 32 + sch*8, lsb[cur^1] + o*512);
      }
    }
    v8s af[4], bfr[4];
    #pragma unroll
    for (int i = 0; i < 4; ++i) {
      af[i]  = *(const v8s*)(lsa[cur] + (mh + i*16 + r16)*32 + quad*8);
      bfr[i] = *(const v8s*)(lsb[cur] + (nh + i*16 + r16)*32 + quad*8);
    }
    #pragma unroll
    for (int i = 0; i < 4; ++i)
      #pragma unroll
      for (int j = 0; j < 4; ++j)
        acc[i][j] = __builtin_amdgcn_mfma_f32_16x16x32_bf16(af[i], bfr[j], acc[i][j], 0, 0, 0);
    cur ^= 1;
  }
}

// Fused QKV projections. grid (8, 32, 3). z==0 pre-scales Q by SCALE_C.
// z==2 writes V transposed: Vt[bh][d][t].
__global__ __launch_bounds__(256, 2) void gemm_qkv(const ushort_t* __restrict__ xn,
    const ushort_t* __restrict__ wtq, const ushort_t* __restrict__ wtk, const ushort_t* __restrict__ wtv,
    const float* __restrict__ bq, const float* __restrict__ bk, const float* __restrict__ bv,
    ushort_t* __restrict__ qo, ushort_t* __restrict__ ko, ushort_t* __restrict__ vto) {
  __shared__ ushort_t lsa[2][128*32];
  __shared__ ushort_t lsb[2][128*32];
  const int z = blockIdx.z;
  const ushort_t* WT = (z == 0) ? wtq : (z == 1) ? wtk : wtv;
  const float* bias  = (z == 0) ? bq  : (z == 1) ? bk  : bv;
  const int m0 = blockIdx.y * 128, n0 = blockIdx.x * 128;
  v4f acc[4][4];
  #pragma unroll
  for (int i = 0; i < 4; ++i)
    #pragma unroll
    for (int j = 0; j < 4; ++j) acc[i][j] = (v4f){0.f, 0.f, 0.f, 0.f};
  gemm_main(lsa, lsb, xn, WT, m0, n0, acc);
  const int tid = threadIdx.x, wid = tid >> 6, lane = tid & 63;
  const int mh = (wid & 1) << 6, nh = (wid >> 1) << 6;
  const int r16 = lane & 15, quad = lane >> 4;
  if (z < 2) {
    ushort_t* out = (z == 0) ? qo : ko;
    const float sc = (z == 0) ? SCALE_C : 1.0f;
    #pragma unroll
    for (int bn = 0; bn < 4; ++bn) {
      const int col = n0 + nh + bn*16 + r16;
      const float bb = bias[col];
      #pragma unroll
      for (int am = 0; am < 4; ++am) {
        const int tb = m0 + mh + am*16 + quad*4;
        #pragma unroll
        for (int r = 0; r < 4; ++r)
          out[(size_t)(tb + r) * DM + col] = f2bf((acc[am][bn][r] + bb) * sc);
      }
    }
  } else {
    #pragma unroll
    for (int bn = 0; bn < 4; ++bn) {
      const int col = n0 + nh + bn*16 + r16;
      const float bb = bias[col];
      const int h = col >> 6, d = col & 63;
      #pragma unroll
      for (int am = 0; am < 4; ++am) {
        const int tb = m0 + mh + am*16 + quad*4;
        const int b = tb >> 11, t = tb & 2047;
        ushort4 o4;
        o4.x = f2bf(acc[am][bn][0] + bb);
        o4.y = f2bf(acc[am][bn][1] + bb);
        o4.z = f2bf(acc[am][bn][2] + bb);
        o4.w = f2bf(acc[am][bn][3] + bb);
        *(ushort4*)(vto + ((size_t)(b*NHEAD + h) * HD + d) * SEQ + t) = o4;
      }
    }
  }
}

// Output projection: fp32 out = A @ WTo^T + bo. grid (8, 32).
__global__ __launch_bounds__(256, 2) void gemm_out(const ushort_t* __restrict__ A,
    const ushort_t* __restrict__ WT, const float* __restrict__ bias,
    float* __restrict__ out) {
  __shared__ ushort_t lsa[2][128*32];
  __shared__ ushort_t lsb[2][128*32];
  const int m0 = blockIdx.y * 128, n0 = blockIdx.x * 128;
  v4f acc[4][4];
  #pragma unroll
  for (int i = 0; i < 4; ++i)
    #pragma unroll
    for (int j = 0; j < 4; ++j) acc[i][j] = (v4f){0.f, 0.f, 0.f, 0.f};
  gemm_main(lsa, lsb, A, WT, m0, n0, acc);
  const int tid = threadIdx.x, wid = tid >> 6, lane = tid & 63;
  const int mh = (wid & 1) << 6, nh = (wid >> 1) << 6;
  const int r16 = lane & 15, quad = lane >> 4;
  #pragma unroll
  for (int bn = 0; bn < 4; ++bn) {
    const int col = n0 + nh + bn*16 + r16;
    const float bb = bias[col];
    #pragma unroll
    for (int am = 0; am < 4; ++am) {
      const int tb = m0 + mh + am*16 + quad*4;
      #pragma unroll
      for (int r = 0; r < 4; ++r)
        out[(size_t)(tb + r) * DM + col] = acc[am][bn][r] + bb;
    }
  }
}

// ---------------- MFMA flash attention v6: double-buffered K/V prefetch ----------------
// grid (SEQ/64, B*NHEAD), 256 threads = 4 waves; wave owns 16 queries.
// 2-phase pipeline: one barrier per 64-key tile; tile t+1's global_load_lds
// issued before tile t's compute so HBM/L2 latency hides under QK+softmax+PV.
// P^T buffer shrunk from PROW=72 pad to PROW=64 + XOR swizzle (T2) so the
// whole block is exactly 40 KiB -> 4 blocks/CU retained.
__global__ __launch_bounds__(256, 4) void attn_kernel(
    const ushort_t* __restrict__ Q, const ushort_t* __restrict__ K,
    const ushort_t* __restrict__ Vt, ushort_t* __restrict__ O) {
  __shared__ ushort_t kbuf[2][8*512];   // (g,half) -> K[key g*16+r16][d half*32+quad*8]
  __shared__ ushort_t vbuf[2][8*512];   // (kb,dg)  -> V^T[d dg*16+r16][key kb*32+quad*8]
  __shared__ ushort_t ptb[4*16*64];     // per-wave P^T, 16 q-rows, XOR-swizzled
  const int tid = threadIdx.x, wid = tid >> 6, lane = tid & 63;
  const int r16 = lane & 15, quad = lane >> 4;
  const int q0 = blockIdx.x * 64, bh = blockIdx.y;
  const int b = bh >> 4, h = bh & 15;
  const ushort_t* gQ = Q + (size_t)b * SEQ * DM + h * HD;
  const ushort_t* gK = K + (size_t)b * SEQ * DM + h * HD;
  const ushort_t* gV = Vt + (size_t)bh * HD * SEQ;

  const int qtok = q0 + wid * 16 + r16;
  const v8s qf0 = *(const v8s*)(gQ + (size_t)qtok * DM + quad * 8);
  const v8s qf1 = *(const v8s*)(gQ + (size_t)qtok * DM + 32 + quad * 8);
  v4f acco[4];
  #pragma unroll
  for (int i = 0; i < 4; ++i) acco[i] = (v4f){0.f, 0.f, 0.f, 0.f};
  float lrun = 0.f;
  ushort_t* ptw = ptb + wid * 1024;       // 2048 B per wave
  const int swz = (r16 & 7) << 4;         // XOR on byte bits 4..6 within a 128B row

  auto stage = [&](int bs, int k0s) {
    if (wid < 2) {
      #pragma unroll
      for (int j = 0; j < 4; ++j) {
        const int o = (wid & 1) * 4 + j;   // 0..7: g = o>>1, half = o&1
        GLOAD16(gK + (size_t)(k0s + (o >> 1) * 16 + r16) * DM + (o & 1) * 32 + quad * 8,
                kbuf[bs] + o * 512);
      }
    } else {
      #pragma unroll
      for (int j = 0; j < 4; ++j) {
        const int o = (wid & 1) * 4 + j;   // 0..7: kb = o>>2, dg = o&3
        GLOAD16(gV + (size_t)((o & 3) * 16 + r16) * SEQ + k0s + (o >> 2) * 32 + quad * 8,
                vbuf[bs] + o * 512);
      }
    }
  };

  stage(0, 0);   // prologue
  int cur = 0;
  for (int kt = 0; kt < SEQ / 64; ++kt) {
    __syncthreads();  // vmcnt drained: buf[cur] ready; buf[cur^1] no longer read
    if (kt + 1 < SEQ / 64) stage(cur ^ 1, (kt + 1) * 64);

    // S^T = K.Q^T : 8 MFMA, linear conflict-free fragment reads
    v4f sacc[4];
    #pragma unroll
    for (int g = 0; g < 4; ++g) sacc[g] = (v4f){0.f, 0.f, 0.f, 0.f};
    #pragma unroll
    for (int g = 0; g < 4; ++g) {
      const v8s ka0 = *(const v8s*)(kbuf[cur] + (g*2 + 0) * 512 + lane * 8);
      const v8s ka1 = *(const v8s*)(kbuf[cur] + (g*2 + 1) * 512 + lane * 8);
      sacc[g] = __builtin_amdgcn_mfma_f32_16x16x32_bf16(ka0, qf0, sacc[g], 0, 0, 0);
      sacc[g] = __builtin_amdgcn_mfma_f32_16x16x32_bf16(ka1, qf1, sacc[g], 0, 0, 0);
    }

    // no-max softmax accumulation (exp2 domain)
    float ls = 0.f;
    #pragma unroll
    for (int g = 0; g < 4; ++g)
      #pragma unroll
      for (int r = 0; r < 4; ++r) {
        const float e = __builtin_amdgcn_exp2f(sacc[g][r]);
        sacc[g][r] = e;
        ls += e;
      }
    ls += __shfl_xor(ls, 16, 64);
    ls += __shfl_xor(ls, 32, 64);
    lrun += ls;

    // P^T -> per-wave LDS (b64 packed writes, XOR-swizzled rows)
    #pragma unroll
    for (int g = 0; g < 4; ++g) {
      uint2 d2;
      d2.x = pack2_bf16(sacc[g][0], sacc[g][1]);
      d2.y = pack2_bf16(sacc[g][2], sacc[g][3]);
      *(uint2*)((char*)ptw + r16 * 128 + ((g * 32 + quad * 8) ^ swz)) = d2;
    }

    // O^T += V^T . P^T : 8 MFMA
    #pragma unroll
    for (int kb = 0; kb < 2; ++kb) {
      const v8s pb = *(const v8s*)((char*)ptw + r16 * 128 + ((kb * 64 + quad * 16) ^ swz));
      #pragma unroll
      for (int dg = 0; dg < 4; ++dg) {
        const v8s vf = *(const v8s*)(vbuf[cur] + (kb*4 + dg) * 512 + lane * 8);
        acco[dg] = __builtin_amdgcn_mfma_f32_16x16x32_bf16(vf, pb, acco[dg], 0, 0, 0);
      }
    }
    cur ^= 1;
  }

  const float inv = 1.f / lrun;
  ushort_t* gO = O + (size_t)b * SEQ * DM + h * HD;
  #pragma unroll
  for (int dg = 0; dg < 4; ++dg) {
    ushort4 o4;
    o4.x = f2bf(acco[dg][0] * inv);
    o4.y = f2bf(acco[dg][1] * inv);
    o4.z = f2bf(acco[dg][2] * inv);
    o4.w = f2bf(acco[dg][3] * inv);
    *(ushort4*)(gO + (size_t)qtok * DM + dg*16 + quad*4) = o4;
  }
}

extern "C" void kernel_launch(void* const* d_in, const int* in_sizes, int n_in,
                              void* d_out, int out_size, void* d_ws, size_t ws_size,
                              hipStream_t stream) {
  const float* x     = (const float*)d_in[0];
  const float* gamma = (const float*)d_in[1];
  const float* beta  = (const float*)d_in[2];
  const float* wq    = (const float*)d_in[3];
  const float* bq    = (const float*)d_in[4];
  const float* wk    = (const float*)d_in[5];
  const float* bk    = (const float*)d_in[6];
  const float* wv    = (const float*)d_in[7];
  const float* bv    = (const float*)d_in[8];
  const float* wo    = (const float*)d_in[9];
  const float* bo    = (const float*)d_in[10];
  float* out = (float*)d_out;

  unsigned char* w8 = (unsigned char*)d_ws;
  const size_t MB = 1024 * 1024;
  ushort_t* xn  = (ushort_t*)(w8 + 0 * MB);   // 8 MB; reused as attention output
  ushort_t* qb  = (ushort_t*)(w8 + 8 * MB);
  ushort_t* kb  = (ushort_t*)(w8 + 16 * MB);
  ushort_t* vt  = (ushort_t*)(w8 + 24 * MB);
  ushort_t* wtq = (ushort_t*)(w8 + 32 * MB);
  ushort_t* wtk = (ushort_t*)(w8 + 34 * MB);
  ushort_t* wtv = (ushort_t*)(w8 + 36 * MB);
  ushort_t* wto = (ushort_t*)(w8 + 38 * MB);
  ushort_t* ob  = xn;

  ln_kernel<<<dim3(NTOK), dim3(256), 0, stream>>>(x, gamma, beta, xn);
  wt_kernel<<<dim3(16, 16, 4), dim3(256), 0, stream>>>(wq, wk, wv, wo, wtq, wtk, wtv, wto);
  gemm_qkv<<<dim3(8, 32, 3), dim3(256), 0, stream>>>(xn, wtq, wtk, wtv, bq, bk, bv, qb, kb, vt);
  attn_kernel<<<dim3(SEQ / 64, 2 * NHEAD), dim3(256), 0, stream>>>(qb, kb, vt, ob);
  gemm_out<<<dim3(8, 32, 1), dim3(256), 0, stream>>>(ob, wto, bo, out);
}

// Round 2
// 219.135 us; speedup vs baseline: 1.0248x; 1.0248x over previous
//
#include <hip/hip_runtime.h>
#include <math.h>

#define SEQ   2048
#define DM    1024
#define NHEAD 16
#define HD    64
#define NTOK  4096
#define EPS   1e-5f
#define SCALE_C 0.18033688f  // 0.125 * log2(e): folded into Q projection

typedef __attribute__((ext_vector_type(8))) short v8s;
typedef __attribute__((ext_vector_type(4))) float v4f;
typedef unsigned short ushort_t;

#define GLOAD16(g, l) __builtin_amdgcn_global_load_lds( \
    (const __attribute__((address_space(1))) unsigned int*)(g), \
    (__attribute__((address_space(3))) unsigned int*)(l), 16, 0, 0)

__device__ __forceinline__ unsigned short f2bf(float f) {
  union { float f; unsigned u; } v; v.f = f;
  unsigned r = v.u + 0x7FFFu + ((v.u >> 16) & 1u);
  return (unsigned short)(r >> 16);
}

// pack two fp32 -> bf16x2 dword (round-half-up): 2 adds + 1 v_perm
__device__ __forceinline__ unsigned pack2_bf16(float a, float b) {
  union { float f; unsigned u; } ua, ub;
  ua.f = a; ub.f = b;
  return __builtin_amdgcn_perm(ub.u + 0x8000u, ua.u + 0x8000u, 0x07060302u);
}

// ---------------- LayerNorm -> bf16 ----------------
__global__ __launch_bounds__(256) void ln_kernel(
    const float* __restrict__ x, const float* __restrict__ g,
    const float* __restrict__ be, ushort_t* __restrict__ y) {
  const int row = blockIdx.x;
  const int t = threadIdx.x;
  const float4 v = ((const float4*)(x + (size_t)row * DM))[t];
  float s  = v.x + v.y + v.z + v.w;
  float ss = v.x*v.x + v.y*v.y + v.z*v.z + v.w*v.w;
  #pragma unroll
  for (int off = 32; off > 0; off >>= 1) {
    s  += __shfl_down(s,  off, 64);
    ss += __shfl_down(ss, off, 64);
  }
  __shared__ float red[8];
  __shared__ float mu_s, rs_s;
  const int wid = t >> 6, lane = t & 63;
  if (lane == 0) { red[wid] = s; red[4 + wid] = ss; }
  __syncthreads();
  if (t == 0) {
    const float S  = red[0] + red[1] + red[2] + red[3];
    const float SS = red[4] + red[5] + red[6] + red[7];
    const float mu  = S * (1.0f / DM);
    const float var = SS * (1.0f / DM) - mu * mu;
    mu_s = mu; rs_s = rsqrtf(var + EPS);
  }
  __syncthreads();
  const float mu = mu_s, r = rs_s;
  const float4 gv = ((const float4*)g)[t];
  const float4 bv = ((const float4*)be)[t];
  ushort4 o;
  o.x = f2bf((v.x - mu) * r * gv.x + bv.x);
  o.y = f2bf((v.y - mu) * r * gv.y + bv.y);
  o.z = f2bf((v.z - mu) * r * gv.z + bv.z);
  o.w = f2bf((v.w - mu) * r * gv.w + bv.w);
  *(ushort4*)(y + (size_t)row * DM + t * 4) = o;
}

// ---------------- W[k][n] fp32 -> WT[n][k] bf16 ----------------
__global__ __launch_bounds__(256) void wt_kernel(
    const float* __restrict__ w0, const float* __restrict__ w1,
    const float* __restrict__ w2, const float* __restrict__ w3,
    ushort_t* __restrict__ o0, ushort_t* __restrict__ o1,
    ushort_t* __restrict__ o2, ushort_t* __restrict__ o3) {
  const int z = blockIdx.z;
  const float* w = (z==0) ? w0 : (z==1) ? w1 : (z==2) ? w2 : w3;
  ushort_t* o    = (z==0) ? o0 : (z==1) ? o1 : (z==2) ? o2 : o3;
  __shared__ float tile[64][65];
  const int t = threadIdx.x;
  const int n0 = blockIdx.x * 64, k0 = blockIdx.y * 64;
  const int r = t >> 4, c4 = (t & 15) * 4;
  #pragma unroll
  for (int i = 0; i < 4; ++i) {
    const float4 v = *(const float4*)(w + (size_t)(k0 + r + i*16) * DM + n0 + c4);
    tile[r + i*16][c4 + 0] = v.x;
    tile[r + i*16][c4 + 1] = v.y;
    tile[r + i*16][c4 + 2] = v.z;
    tile[r + i*16][c4 + 3] = v.w;
  }
  __syncthreads();
  #pragma unroll
  for (int i = 0; i < 4; ++i) {
    const int n = r + i*16;
    ushort4 o4;
    o4.x = f2bf(tile[c4 + 0][n]);
    o4.y = f2bf(tile[c4 + 1][n]);
    o4.z = f2bf(tile[c4 + 2][n]);
    o4.w = f2bf(tile[c4 + 3][n]);
    *(ushort4*)(o + (size_t)(n0 + n) * DM + k0 + c4) = o4;
  }
}

// ---------------- bf16 MFMA GEMM mainloop (m97 structure, round-0 known-good) ----------------
__device__ __forceinline__ void gemm_main(ushort_t* lsa, ushort_t* lsb,
    const ushort_t* A, const ushort_t* WT, int m0, int n0, v4f acc[4][4]) {
  const int tid = threadIdx.x;
  const int wid = tid >> 6, lane = tid & 63;
  const int mh = (wid & 1) << 6, nh = (wid >> 1) << 6;
  const int r16 = lane & 15, quad = lane >> 4;
  const int srow = lane >> 2, sch = lane & 3;
  for (int k0 = 0; k0 < DM; k0 += 32) {
    __syncthreads();
    #pragma unroll
    for (int j = 0; j < 2; ++j) {
      const int o = wid * 2 + j;
      GLOAD16(A  + (size_t)(m0 + o*16 + srow) * DM + k0 + sch*8, lsa + o*512);
      GLOAD16(WT + (size_t)(n0 + o*16 + srow) * DM + k0 + sch*8, lsb + o*512);
    }
    __syncthreads();
    v8s af[4], bfr[4];
    #pragma unroll
    for (int i = 0; i < 4; ++i) {
      af[i]  = *(const v8s*)(lsa + (mh + i*16 + r16)*32 + quad*8);
      bfr[i] = *(const v8s*)(lsb + (nh + i*16 + r16)*32 + quad*8);
    }
    #pragma unroll
    for (int i = 0; i < 4; ++i)
      #pragma unroll
      for (int j = 0; j < 4; ++j)
        acc[i][j] = __builtin_amdgcn_mfma_f32_16x16x32_bf16(af[i], bfr[j], acc[i][j], 0, 0, 0);
  }
}

// Fused QKV projections. grid (8, 32, 3). z==0 pre-scales Q by SCALE_C.
// z==2 writes V transposed: Vt[bh][d][t].
__global__ __launch_bounds__(256, 2) void gemm_qkv(const ushort_t* __restrict__ xn,
    const ushort_t* __restrict__ wtq, const ushort_t* __restrict__ wtk, const ushort_t* __restrict__ wtv,
    const float* __restrict__ bq, const float* __restrict__ bk, const float* __restrict__ bv,
    ushort_t* __restrict__ qo, ushort_t* __restrict__ ko, ushort_t* __restrict__ vto) {
  __shared__ ushort_t lsa[128*32];
  __shared__ ushort_t lsb[128*32];
  const int z = blockIdx.z;
  const ushort_t* WT = (z == 0) ? wtq : (z == 1) ? wtk : wtv;
  const float* bias  = (z == 0) ? bq  : (z == 1) ? bk  : bv;
  const int m0 = blockIdx.y * 128, n0 = blockIdx.x * 128;
  v4f acc[4][4];
  #pragma unroll
  for (int i = 0; i < 4; ++i)
    #pragma unroll
    for (int j = 0; j < 4; ++j) acc[i][j] = (v4f){0.f, 0.f, 0.f, 0.f};
  gemm_main(lsa, lsb, xn, WT, m0, n0, acc);
  const int tid = threadIdx.x, wid = tid >> 6, lane = tid & 63;
  const int mh = (wid & 1) << 6, nh = (wid >> 1) << 6;
  const int r16 = lane & 15, quad = lane >> 4;
  if (z < 2) {
    ushort_t* out = (z == 0) ? qo : ko;
    const float sc = (z == 0) ? SCALE_C : 1.0f;
    #pragma unroll
    for (int bn = 0; bn < 4; ++bn) {
      const int col = n0 + nh + bn*16 + r16;
      const float bb = bias[col];
      #pragma unroll
      for (int am = 0; am < 4; ++am) {
        const int tb = m0 + mh + am*16 + quad*4;
        #pragma unroll
        for (int r = 0; r < 4; ++r)
          out[(size_t)(tb + r) * DM + col] = f2bf((acc[am][bn][r] + bb) * sc);
      }
    }
  } else {
    #pragma unroll
    for (int bn = 0; bn < 4; ++bn) {
      const int col = n0 + nh + bn*16 + r16;
      const float bb = bias[col];
      const int h = col >> 6, d = col & 63;
      #pragma unroll
      for (int am = 0; am < 4; ++am) {
        const int tb = m0 + mh + am*16 + quad*4;
        const int b = tb >> 11, t = tb & 2047;
        ushort4 o4;
        o4.x = f2bf(acc[am][bn][0] + bb);
        o4.y = f2bf(acc[am][bn][1] + bb);
        o4.z = f2bf(acc[am][bn][2] + bb);
        o4.w = f2bf(acc[am][bn][3] + bb);
        *(ushort4*)(vto + ((size_t)(b*NHEAD + h) * HD + d) * SEQ + t) = o4;
      }
    }
  }
}

// Output projection: fp32 out = A @ WTo^T + bo. grid (8, 32).
__global__ __launch_bounds__(256, 2) void gemm_out(const ushort_t* __restrict__ A,
    const ushort_t* __restrict__ WT, const float* __restrict__ bias,
    float* __restrict__ out) {
  __shared__ ushort_t lsa[128*32];
  __shared__ ushort_t lsb[128*32];
  const int m0 = blockIdx.y * 128, n0 = blockIdx.x * 128;
  v4f acc[4][4];
  #pragma unroll
  for (int i = 0; i < 4; ++i)
    #pragma unroll
    for (int j = 0; j < 4; ++j) acc[i][j] = (v4f){0.f, 0.f, 0.f, 0.f};
  gemm_main(lsa, lsb, A, WT, m0, n0, acc);
  const int tid = threadIdx.x, wid = tid >> 6, lane = tid & 63;
  const int mh = (wid & 1) << 6, nh = (wid >> 1) << 6;
  const int r16 = lane & 15, quad = lane >> 4;
  #pragma unroll
  for (int bn = 0; bn < 4; ++bn) {
    const int col = n0 + nh + bn*16 + r16;
    const float bb = bias[col];
    #pragma unroll
    for (int am = 0; am < 4; ++am) {
      const int tb = m0 + mh + am*16 + quad*4;
      #pragma unroll
      for (int r = 0; r < 4; ++r)
        out[(size_t)(tb + r) * DM + col] = acc[am][bn][r] + bb;
    }
  }
}

// ---------------- MFMA flash attention v7: K-dbuf + counted-vmcnt V pipeline ----------------
// grid (SEQ/64, B*NHEAD), 256 threads = 4 waves; wave owns 16 queries.
// LDS = 16K (K dbuf) + 8K (V single) + 8K (swizzled P^T) = 32 KiB -> 4 blocks/CU.
// Per tile: each wave issues 2 V-loads (this tile) then 2 K-loads (next tile);
// QK^T + softmax run with both in flight; s_waitcnt vmcnt(2) completes only V
// (K-next stays in flight across the barrier, T4); PV; loop. K latency hides
// under a full iteration, V latency under QK+softmax. Last iter prefetches
// K[0] again (wraparound) so the vmcnt count stays uniform.
__global__ __launch_bounds__(256, 4) void attn_kernel(
    const ushort_t* __restrict__ Q, const ushort_t* __restrict__ K,
    const ushort_t* __restrict__ Vt, ushort_t* __restrict__ O) {
  __shared__ ushort_t kbuf[2][8*512];   // (g,half) -> K[key g*16+r16][d half*32+quad*8]
  __shared__ ushort_t vbuf[8*512];      // (kb,dg)  -> V^T[d dg*16+r16][key kb*32+quad*8]
  __shared__ ushort_t ptb[4*16*64];     // per-wave P^T, 16 q-rows, XOR-swizzled
  const int tid = threadIdx.x, wid = tid >> 6, lane = tid & 63;
  const int r16 = lane & 15, quad = lane >> 4;
  const int q0 = blockIdx.x * 64, bh = blockIdx.y;
  const int b = bh >> 4, h = bh & 15;
  const ushort_t* gQ = Q + (size_t)b * SEQ * DM + h * HD;
  const ushort_t* gK = K + (size_t)b * SEQ * DM + h * HD;
  const ushort_t* gV = Vt + (size_t)bh * HD * SEQ;

  const int qtok = q0 + wid * 16 + r16;
  const v8s qf0 = *(const v8s*)(gQ + (size_t)qtok * DM + quad * 8);
  const v8s qf1 = *(const v8s*)(gQ + (size_t)qtok * DM + 32 + quad * 8);
  v4f acco[4];
  #pragma unroll
  for (int i = 0; i < 4; ++i) acco[i] = (v4f){0.f, 0.f, 0.f, 0.f};
  float lrun = 0.f;
  ushort_t* ptw = ptb + wid * 1024;       // 2048 B per wave, private
  const int swz = (r16 & 7) << 4;         // XOR on byte bits 4..6 within a 128B row

  // each wave stages 2 of the 8 K-chunks: o = wid*2 + j; g = o>>1, half = o&1
  auto stageK = [&](int bs, int k0s) {
    #pragma unroll
    for (int j = 0; j < 2; ++j) {
      const int o = wid * 2 + j;
      GLOAD16(gK + (size_t)(k0s + (o >> 1) * 16 + r16) * DM + (o & 1) * 32 + quad * 8,
              kbuf[bs] + o * 512);
    }
  };
  // each wave stages 2 of the 8 V-chunks: o = wid*2 + j; kb = o>>2, dg = o&3
  auto stageV = [&](int k0s) {
    #pragma unroll
    for (int j = 0; j < 2; ++j) {
      const int o = wid * 2 + j;
      GLOAD16(gV + (size_t)((o & 3) * 16 + r16) * SEQ + k0s + (o >> 2) * 32 + quad * 8,
              vbuf + o * 512);
    }
  };

  stageK(0, 0);   // prologue: K[0] in flight (2 loads/wave)
  int cur = 0;
  for (int kt = 0; kt < SEQ / 64; ++kt) {
    // K[cur] landed (own wave's 2 loads); barrier -> everyone's chunks visible
    asm volatile("s_waitcnt vmcnt(0)" ::: "memory");
    __builtin_amdgcn_s_barrier();

    stageV(kt * 64);                           // V for THIS tile (issued first)
    stageK(cur ^ 1, ((kt + 1) & 31) * 64);     // K for NEXT tile (wraparound on last)

    // S^T = K.Q^T : 8 MFMA, linear conflict-free fragment reads
    v4f sacc[4];
    #pragma unroll
    for (int g = 0; g < 4; ++g) sacc[g] = (v4f){0.f, 0.f, 0.f, 0.f};
    #pragma unroll
    for (int g = 0; g < 4; ++g) {
      const v8s ka0 = *(const v8s*)(kbuf[cur] + (g*2 + 0) * 512 + lane * 8);
      const v8s ka1 = *(const v8s*)(kbuf[cur] + (g*2 + 1) * 512 + lane * 8);
      sacc[g] = __builtin_amdgcn_mfma_f32_16x16x32_bf16(ka0, qf0, sacc[g], 0, 0, 0);
      sacc[g] = __builtin_amdgcn_mfma_f32_16x16x32_bf16(ka1, qf1, sacc[g], 0, 0, 0);
    }

    // no-max softmax accumulation (exp2 domain)
    float ls = 0.f;
    #pragma unroll
    for (int g = 0; g < 4; ++g)
      #pragma unroll
      for (int r = 0; r < 4; ++r) {
        const float e = __builtin_amdgcn_exp2f(sacc[g][r]);
        sacc[g][r] = e;
        ls += e;
      }
    ls += __shfl_xor(ls, 16, 64);
    ls += __shfl_xor(ls, 32, 64);
    lrun += ls;

    // P^T -> per-wave LDS (b64 packed writes, XOR-swizzled rows)
    #pragma unroll
    for (int g = 0; g < 4; ++g) {
      uint2 d2;
      d2.x = pack2_bf16(sacc[g][0], sacc[g][1]);
      d2.y = pack2_bf16(sacc[g][2], sacc[g][3]);
      *(uint2*)((char*)ptw + r16 * 128 + ((g * 32 + quad * 8) ^ swz)) = d2;
    }

    // wait V only (2 oldest); K-next (2 newest) stays in flight across barrier
    asm volatile("s_waitcnt vmcnt(2)" ::: "memory");
    __builtin_amdgcn_s_barrier();

    // O^T += V^T . P^T : 8 MFMA
    #pragma unroll
    for (int kb = 0; kb < 2; ++kb) {
      const v8s pb = *(const v8s*)((char*)ptw + r16 * 128 + ((kb * 64 + quad * 16) ^ swz));
      #pragma unroll
      for (int dg = 0; dg < 4; ++dg) {
        const v8s vf = *(const v8s*)(vbuf + (kb*4 + dg) * 512 + lane * 8);
        acco[dg] = __builtin_amdgcn_mfma_f32_16x16x32_bf16(vf, pb, acco[dg], 0, 0, 0);
      }
    }
    cur ^= 1;
  }

  const float inv = 1.f / lrun;
  ushort_t* gO = O + (size_t)b * SEQ * DM + h * HD;
  #pragma unroll
  for (int dg = 0; dg < 4; ++dg) {
    ushort4 o4;
    o4.x = f2bf(acco[dg][0] * inv);
    o4.y = f2bf(acco[dg][1] * inv);
    o4.z = f2bf(acco[dg][2] * inv);
    o4.w = f2bf(acco[dg][3] * inv);
    *(ushort4*)(gO + (size_t)qtok * DM + dg*16 + quad*4) = o4;
  }
}

extern "C" void kernel_launch(void* const* d_in, const int* in_sizes, int n_in,
                              void* d_out, int out_size, void* d_ws, size_t ws_size,
                              hipStream_t stream) {
  const float* x     = (const float*)d_in[0];
  const float* gamma = (const float*)d_in[1];
  const float* beta  = (const float*)d_in[2];
  const float* wq    = (const float*)d_in[3];
  const float* bq    = (const float*)d_in[4];
  const float* wk    = (const float*)d_in[5];
  const float* bk    = (const float*)d_in[6];
  const float* wv    = (const float*)d_in[7];
  const float* bv    = (const float*)d_in[8];
  const float* wo    = (const float*)d_in[9];
  const float* bo    = (const float*)d_in[10];
  float* out = (float*)d_out;

  unsigned char* w8 = (unsigned char*)d_ws;
  const size_t MB = 1024 * 1024;
  ushort_t* xn  = (ushort_t*)(w8 + 0 * MB);   // 8 MB; reused as attention output
  ushort_t* qb  = (ushort_t*)(w8 + 8 * MB);
  ushort_t* kb  = (ushort_t*)(w8 + 16 * MB);
  ushort_t* vt  = (ushort_t*)(w8 + 24 * MB);
  ushort_t* wtq = (ushort_t*)(w8 + 32 * MB);
  ushort_t* wtk = (ushort_t*)(w8 + 34 * MB);
  ushort_t* wtv = (ushort_t*)(w8 + 36 * MB);
  ushort_t* wto = (ushort_t*)(w8 + 38 * MB);
  ushort_t* ob  = xn;

  ln_kernel<<<dim3(NTOK), dim3(256), 0, stream>>>(x, gamma, beta, xn);
  wt_kernel<<<dim3(16, 16, 4), dim3(256), 0, stream>>>(wq, wk, wv, wo, wtq, wtk, wtv, wto);
  gemm_qkv<<<dim3(8, 32, 3), dim3(256), 0, stream>>>(xn, wtq, wtk, wtv, bq, bk, bv, qb, kb, vt);
  attn_kernel<<<dim3(SEQ / 64, 2 * NHEAD), dim3(256), 0, stream>>>(qb, kb, vt, ob);
  gemm_out<<<dim3(8, 32, 1), dim3(256), 0, stream>>>(ob, wto, bo, out);
}

// Round 3
// 217.665 us; speedup vs baseline: 1.0318x; 1.0068x over previous
//
#include <hip/hip_runtime.h>
#include <math.h>

#define SEQ   2048
#define DM    1024
#define NHEAD 16
#define HD    64
#define NTOK  4096
#define EPS   1e-5f
#define SCALE_C 0.18033688f  // 0.125 * log2(e): folded into Q projection

typedef __attribute__((ext_vector_type(8))) short v8s;
typedef __attribute__((ext_vector_type(4))) short v4s;
typedef __attribute__((ext_vector_type(4))) float v4f;
typedef unsigned short ushort_t;

#define GLOAD16(g, l) __builtin_amdgcn_global_load_lds( \
    (const __attribute__((address_space(1))) unsigned int*)(g), \
    (__attribute__((address_space(3))) unsigned int*)(l), 16, 0, 0)

// K=16 bf16 MFMA: B-frag layout (k=quad*4+e, n=lane&15) matches 16x16 C-layout,
// so QK scores feed PV directly from registers.
#if defined(__has_builtin)
#if __has_builtin(__builtin_amdgcn_mfma_f32_16x16x16_bf16)
#define MFMA16(va, vb, vc) __builtin_amdgcn_mfma_f32_16x16x16_bf16(va, vb, vc, 0, 0, 0)
#elif __has_builtin(__builtin_amdgcn_mfma_f32_16x16x16bf16_1k)
#define MFMA16(va, vb, vc) __builtin_amdgcn_mfma_f32_16x16x16bf16_1k(va, vb, vc, 0, 0, 0)
#endif
#endif
#ifndef MFMA16
__device__ __forceinline__ v4f mfma16_asm(v4s a, v4s b, v4f c) {
  asm volatile("s_nop 2\n\tv_mfma_f32_16x16x16_bf16 %0, %1, %2, %0\n\ts_nop 4"
               : "+v"(c) : "v"(a), "v"(b));
  return c;
}
#define MFMA16(va, vb, vc) mfma16_asm(va, vb, vc)
#endif

__device__ __forceinline__ unsigned short f2bf(float f) {
  union { float f; unsigned u; } v; v.f = f;
  unsigned r = v.u + 0x7FFFu + ((v.u >> 16) & 1u);
  return (unsigned short)(r >> 16);
}

// pack two fp32 -> bf16x2 dword (round-half-up): 2 adds + 1 v_perm
__device__ __forceinline__ unsigned pack2_bf16(float a, float b) {
  union { float f; unsigned u; } ua, ub;
  ua.f = a; ub.f = b;
  return __builtin_amdgcn_perm(ub.u + 0x8000u, ua.u + 0x8000u, 0x07060302u);
}

// ---------------- LayerNorm -> bf16 ----------------
__global__ __launch_bounds__(256) void ln_kernel(
    const float* __restrict__ x, const float* __restrict__ g,
    const float* __restrict__ be, ushort_t* __restrict__ y) {
  const int row = blockIdx.x;
  const int t = threadIdx.x;
  const float4 v = ((const float4*)(x + (size_t)row * DM))[t];
  float s  = v.x + v.y + v.z + v.w;
  float ss = v.x*v.x + v.y*v.y + v.z*v.z + v.w*v.w;
  #pragma unroll
  for (int off = 32; off > 0; off >>= 1) {
    s  += __shfl_down(s,  off, 64);
    ss += __shfl_down(ss, off, 64);
  }
  __shared__ float red[8];
  __shared__ float mu_s, rs_s;
  const int wid = t >> 6, lane = t & 63;
  if (lane == 0) { red[wid] = s; red[4 + wid] = ss; }
  __syncthreads();
  if (t == 0) {
    const float S  = red[0] + red[1] + red[2] + red[3];
    const float SS = red[4] + red[5] + red[6] + red[7];
    const float mu  = S * (1.0f / DM);
    const float var = SS * (1.0f / DM) - mu * mu;
    mu_s = mu; rs_s = rsqrtf(var + EPS);
  }
  __syncthreads();
  const float mu = mu_s, r = rs_s;
  const float4 gv = ((const float4*)g)[t];
  const float4 bv = ((const float4*)be)[t];
  ushort4 o;
  o.x = f2bf((v.x - mu) * r * gv.x + bv.x);
  o.y = f2bf((v.y - mu) * r * gv.y + bv.y);
  o.z = f2bf((v.z - mu) * r * gv.z + bv.z);
  o.w = f2bf((v.w - mu) * r * gv.w + bv.w);
  *(ushort4*)(y + (size_t)row * DM + t * 4) = o;
}

// ---------------- W[k][n] fp32 -> WT[n][k] bf16 ----------------
__global__ __launch_bounds__(256) void wt_kernel(
    const float* __restrict__ w0, const float* __restrict__ w1,
    const float* __restrict__ w2, const float* __restrict__ w3,
    ushort_t* __restrict__ o0, ushort_t* __restrict__ o1,
    ushort_t* __restrict__ o2, ushort_t* __restrict__ o3) {
  const int z = blockIdx.z;
  const float* w = (z==0) ? w0 : (z==1) ? w1 : (z==2) ? w2 : w3;
  ushort_t* o    = (z==0) ? o0 : (z==1) ? o1 : (z==2) ? o2 : o3;
  __shared__ float tile[64][65];
  const int t = threadIdx.x;
  const int n0 = blockIdx.x * 64, k0 = blockIdx.y * 64;
  const int r = t >> 4, c4 = (t & 15) * 4;
  #pragma unroll
  for (int i = 0; i < 4; ++i) {
    const float4 v = *(const float4*)(w + (size_t)(k0 + r + i*16) * DM + n0 + c4);
    tile[r + i*16][c4 + 0] = v.x;
    tile[r + i*16][c4 + 1] = v.y;
    tile[r + i*16][c4 + 2] = v.z;
    tile[r + i*16][c4 + 3] = v.w;
  }
  __syncthreads();
  #pragma unroll
  for (int i = 0; i < 4; ++i) {
    const int n = r + i*16;
    ushort4 o4;
    o4.x = f2bf(tile[c4 + 0][n]);
    o4.y = f2bf(tile[c4 + 1][n]);
    o4.z = f2bf(tile[c4 + 2][n]);
    o4.w = f2bf(tile[c4 + 3][n]);
    *(ushort4*)(o + (size_t)(n0 + n) * DM + k0 + c4) = o4;
  }
}

// ---------------- bf16 MFMA GEMM mainloop (m97 structure, known-good) ----------------
__device__ __forceinline__ void gemm_main(ushort_t* lsa, ushort_t* lsb,
    const ushort_t* A, const ushort_t* WT, int m0, int n0, v4f acc[4][4]) {
  const int tid = threadIdx.x;
  const int wid = tid >> 6, lane = tid & 63;
  const int mh = (wid & 1) << 6, nh = (wid >> 1) << 6;
  const int r16 = lane & 15, quad = lane >> 4;
  const int srow = lane >> 2, sch = lane & 3;
  for (int k0 = 0; k0 < DM; k0 += 32) {
    __syncthreads();
    #pragma unroll
    for (int j = 0; j < 2; ++j) {
      const int o = wid * 2 + j;
      GLOAD16(A  + (size_t)(m0 + o*16 + srow) * DM + k0 + sch*8, lsa + o*512);
      GLOAD16(WT + (size_t)(n0 + o*16 + srow) * DM + k0 + sch*8, lsb + o*512);
    }
    __syncthreads();
    v8s af[4], bfr[4];
    #pragma unroll
    for (int i = 0; i < 4; ++i) {
      af[i]  = *(const v8s*)(lsa + (mh + i*16 + r16)*32 + quad*8);
      bfr[i] = *(const v8s*)(lsb + (nh + i*16 + r16)*32 + quad*8);
    }
    #pragma unroll
    for (int i = 0; i < 4; ++i)
      #pragma unroll
      for (int j = 0; j < 4; ++j)
        acc[i][j] = __builtin_amdgcn_mfma_f32_16x16x32_bf16(af[i], bfr[j], acc[i][j], 0, 0, 0);
  }
}

// Fused QKV projections. grid (8, 32, 3). z==0 pre-scales Q by SCALE_C.
// z==2 writes V in PV-fragment-linear tile layout (see attn_kernel vbuf):
//   idx = bh*131072 + (t>>6)*4096 + (((t>>4)&3)*4 + (d>>4))*256 + ((t>>2)&3)*64 + (d&15)*4 + (t&3)
__global__ __launch_bounds__(256, 2) void gemm_qkv(const ushort_t* __restrict__ xn,
    const ushort_t* __restrict__ wtq, const ushort_t* __restrict__ wtk, const ushort_t* __restrict__ wtv,
    const float* __restrict__ bq, const float* __restrict__ bk, const float* __restrict__ bv,
    ushort_t* __restrict__ qo, ushort_t* __restrict__ ko, ushort_t* __restrict__ vto) {
  __shared__ ushort_t lsa[128*32];
  __shared__ ushort_t lsb[128*32];
  const int z = blockIdx.z;
  const ushort_t* WT = (z == 0) ? wtq : (z == 1) ? wtk : wtv;
  const float* bias  = (z == 0) ? bq  : (z == 1) ? bk  : bv;
  const int m0 = blockIdx.y * 128, n0 = blockIdx.x * 128;
  v4f acc[4][4];
  #pragma unroll
  for (int i = 0; i < 4; ++i)
    #pragma unroll
    for (int j = 0; j < 4; ++j) acc[i][j] = (v4f){0.f, 0.f, 0.f, 0.f};
  gemm_main(lsa, lsb, xn, WT, m0, n0, acc);
  const int tid = threadIdx.x, wid = tid >> 6, lane = tid & 63;
  const int mh = (wid & 1) << 6, nh = (wid >> 1) << 6;
  const int r16 = lane & 15, quad = lane >> 4;
  if (z < 2) {
    ushort_t* out = (z == 0) ? qo : ko;
    const float sc = (z == 0) ? SCALE_C : 1.0f;
    #pragma unroll
    for (int bn = 0; bn < 4; ++bn) {
      const int col = n0 + nh + bn*16 + r16;
      const float bb = bias[col];
      #pragma unroll
      for (int am = 0; am < 4; ++am) {
        const int tb = m0 + mh + am*16 + quad*4;
        #pragma unroll
        for (int r = 0; r < 4; ++r)
          out[(size_t)(tb + r) * DM + col] = f2bf((acc[am][bn][r] + bb) * sc);
      }
    }
  } else {
    #pragma unroll
    for (int bn = 0; bn < 4; ++bn) {
      const int col = n0 + nh + bn*16 + r16;
      const float bb = bias[col];
      const int h = col >> 6, d = col & 63;
      #pragma unroll
      for (int am = 0; am < 4; ++am) {
        const int tb = m0 + mh + am*16 + quad*4;
        const int b = tb >> 11, t = tb & 2047;   // t % 4 == 0
        const int bh = b * NHEAD + h;
        ushort4 o4;
        o4.x = f2bf(acc[am][bn][0] + bb);
        o4.y = f2bf(acc[am][bn][1] + bb);
        o4.z = f2bf(acc[am][bn][2] + bb);
        o4.w = f2bf(acc[am][bn][3] + bb);
        const size_t idx = (size_t)bh * 131072 + (size_t)(t >> 6) * 4096 +
                           (size_t)((((t >> 4) & 3) * 4) + (d >> 4)) * 256 +
                           ((t >> 2) & 3) * 64 + (d & 15) * 4;
        *(ushort4*)(vto + idx) = o4;
      }
    }
  }
}

// Output projection: fp32 out = A @ WTo^T + bo. grid (8, 32).
__global__ __launch_bounds__(256, 2) void gemm_out(const ushort_t* __restrict__ A,
    const ushort_t* __restrict__ WT, const float* __restrict__ bias,
    float* __restrict__ out) {
  __shared__ ushort_t lsa[128*32];
  __shared__ ushort_t lsb[128*32];
  const int m0 = blockIdx.y * 128, n0 = blockIdx.x * 128;
  v4f acc[4][4];
  #pragma unroll
  for (int i = 0; i < 4; ++i)
    #pragma unroll
    for (int j = 0; j < 4; ++j) acc[i][j] = (v4f){0.f, 0.f, 0.f, 0.f};
  gemm_main(lsa, lsb, A, WT, m0, n0, acc);
  const int tid = threadIdx.x, wid = tid >> 6, lane = tid & 63;
  const int mh = (wid & 1) << 6, nh = (wid >> 1) << 6;
  const int r16 = lane & 15, quad = lane >> 4;
  #pragma unroll
  for (int bn = 0; bn < 4; ++bn) {
    const int col = n0 + nh + bn*16 + r16;
    const float bb = bias[col];
    #pragma unroll
    for (int am = 0; am < 4; ++am) {
      const int tb = m0 + mh + am*16 + quad*4;
      #pragma unroll
      for (int r = 0; r < 4; ++r)
        out[(size_t)(tb + r) * DM + col] = acc[am][bn][r] + bb;
    }
  }
}

// ---------------- MFMA flash attention v8: key-split + in-register P ----------------
// SPLIT=1: grid (32, 32, 2) = 2048 blocks = 8/CU = 32 waves/CU. Each z-half sums
// its 1024 keys (no-max exp2 softmax => partials are additive); fp32 O-partials
// + l-partials to global; combine_kernel merges. SPLIT=0 fallback: one pass,
// normalized bf16 out.
// P stays in registers: PV uses 16x16x16 MFMA whose B-frag layout equals the QK
// C-layout. LDS = kbuf 8K + vbuf 8K = 16 KiB. All LDS reads conflict-free.
#define OHALF ((size_t)32 * 2048 * 64)   // floats per half of Opart
#define LHALF (32 * 2048)                // floats per half of lpart
template<int SPLIT>
__global__ __launch_bounds__(256, 8) void attn_kernel(
    const ushort_t* __restrict__ Q, const ushort_t* __restrict__ K,
    const ushort_t* __restrict__ Vt, ushort_t* __restrict__ O,
    float* __restrict__ Opart, float* __restrict__ lpart) {
  __shared__ ushort_t kbuf[8*512];   // chunk(g,half): K[key g*16+r16][d half*32+quad*8]
  __shared__ ushort_t vbuf[16*256];  // chunk(g,dg):   V^T frag-linear, 512B chunks
  const int tid = threadIdx.x, wid = tid >> 6, lane = tid & 63;
  const int r16 = lane & 15, quad = lane >> 4;
  const int q0 = blockIdx.x * 64, bh = blockIdx.y;
  const int half = SPLIT ? blockIdx.z : 0;
  const int b = bh >> 4, h = bh & 15;
  const ushort_t* gQ = Q + (size_t)b * SEQ * DM + h * HD;
  const ushort_t* gK = K + (size_t)b * SEQ * DM + h * HD;
  const ushort_t* gV = Vt + (size_t)bh * 131072;

  const int qtok = q0 + wid * 16 + r16;
  const v8s qf0 = *(const v8s*)(gQ + (size_t)qtok * DM + quad * 8);
  const v8s qf1 = *(const v8s*)(gQ + (size_t)qtok * DM + 32 + quad * 8);
  v4f acco[4];
  #pragma unroll
  for (int i = 0; i < 4; ++i) acco[i] = (v4f){0.f, 0.f, 0.f, 0.f};
  float lrun = 0.f;

  const int NIT = SPLIT ? (SEQ / 128) : (SEQ / 64);
  const int kt0 = half * NIT;
  for (int it = 0; it < NIT; ++it) {
    const int kt = kt0 + it;
    const int k0 = kt * 64;
    __syncthreads();   // previous tile's reads done; buffers reusable
    // stage K: 8 chunks (1 KiB each), 2 per wave
    #pragma unroll
    for (int j = 0; j < 2; ++j) {
      const int o = wid * 2 + j;   // g = o>>1, dhalf = o&1
      GLOAD16(gK + (size_t)(k0 + (o >> 1) * 16 + r16) * DM + (o & 1) * 32 + quad * 8,
              kbuf + o * 512);
    }
    // stage V: contiguous 8 KiB tile image, 2 GLOADs per wave
    #pragma unroll
    for (int j = 0; j < 2; ++j) {
      const int o = wid * 2 + j;
      GLOAD16(gV + (size_t)kt * 4096 + o * 512 + lane * 8, vbuf + o * 512);
    }
    __syncthreads();   // vmcnt drained by barrier: staged data visible

    // S^T = K.Q^T : 8 MFMA (16x16x32), conflict-free linear fragment reads
    v4f sacc[4];
    #pragma unroll
    for (int g = 0; g < 4; ++g) sacc[g] = (v4f){0.f, 0.f, 0.f, 0.f};
    #pragma unroll
    for (int g = 0; g < 4; ++g) {
      const v8s ka0 = *(const v8s*)(kbuf + (g*2 + 0) * 512 + lane * 8);
      const v8s ka1 = *(const v8s*)(kbuf + (g*2 + 1) * 512 + lane * 8);
      sacc[g] = __builtin_amdgcn_mfma_f32_16x16x32_bf16(ka0, qf0, sacc[g], 0, 0, 0);
      sacc[g] = __builtin_amdgcn_mfma_f32_16x16x32_bf16(ka1, qf1, sacc[g], 0, 0, 0);
    }

    // no-max softmax (exp2 domain) -> in-register PV B-fragments
    float ls = 0.f;
    v4s pfrag[4];
    #pragma unroll
    for (int g = 0; g < 4; ++g) {
      float e0 = __builtin_amdgcn_exp2f(sacc[g][0]);
      float e1 = __builtin_amdgcn_exp2f(sacc[g][1]);
      float e2 = __builtin_amdgcn_exp2f(sacc[g][2]);
      float e3 = __builtin_amdgcn_exp2f(sacc[g][3]);
      ls += (e0 + e1) + (e2 + e3);
      union { v4s s; uint2 u; } pk;
      pk.u.x = pack2_bf16(e0, e1);
      pk.u.y = pack2_bf16(e2, e3);
      pfrag[g] = pk.s;
    }
    ls += __shfl_xor(ls, 16, 64);
    ls += __shfl_xor(ls, 32, 64);
    lrun += ls;

    // O^T += V^T . P : 16 MFMA (16x16x16), P from registers, V conflict-free
    #pragma unroll
    for (int dg = 0; dg < 4; ++dg) {
      #pragma unroll
      for (int g = 0; g < 4; ++g) {
        const v4s vf = *(const v4s*)(vbuf + (g*4 + dg) * 256 + quad * 64 + r16 * 4);
        acco[dg] = MFMA16(vf, pfrag[g], acco[dg]);
      }
    }
  }

  if (SPLIT) {
    float* Op = Opart + half * OHALF + ((size_t)bh * SEQ + qtok) * 64;
    #pragma unroll
    for (int dg = 0; dg < 4; ++dg)
      *(v4f*)(Op + dg*16 + quad*4) = acco[dg];
    if (quad == 0) lpart[half * LHALF + bh * SEQ + qtok] = lrun;
  } else {
    const float inv = 1.f / lrun;
    ushort_t* gO = O + (size_t)b * SEQ * DM + h * HD;
    #pragma unroll
    for (int dg = 0; dg < 4; ++dg) {
      ushort4 o4;
      o4.x = f2bf(acco[dg][0] * inv);
      o4.y = f2bf(acco[dg][1] * inv);
      o4.z = f2bf(acco[dg][2] * inv);
      o4.w = f2bf(acco[dg][3] * inv);
      *(ushort4*)(gO + (size_t)qtok * DM + dg*16 + quad*4) = o4;
    }
  }
}

// combine: ob[tok][h*64+d] = (O0+O1)/(l0+l1), bf16. grid (4096), 256 thr x 4 elems.
__global__ __launch_bounds__(256) void combine_kernel(
    const float* __restrict__ Opart, const float* __restrict__ lpart,
    ushort_t* __restrict__ ob) {
  const int tok = blockIdx.x;
  const int b = tok >> 11, t = tok & 2047;
  const int dm0 = threadIdx.x * 4;
  const int h = dm0 >> 6, d = dm0 & 63;
  const int bh = b * NHEAD + h;
  const size_t idx = ((size_t)bh * SEQ + t) * 64 + d;
  const float4 a = *(const float4*)(Opart + idx);
  const float4 c = *(const float4*)(Opart + OHALF + idx);
  const float l = lpart[bh * SEQ + t] + lpart[LHALF + bh * SEQ + t];
  const float inv = 1.f / l;
  ushort4 o4;
  o4.x = f2bf((a.x + c.x) * inv);
  o4.y = f2bf((a.y + c.y) * inv);
  o4.z = f2bf((a.z + c.z) * inv);
  o4.w = f2bf((a.w + c.w) * inv);
  *(ushort4*)(ob + (size_t)tok * DM + dm0) = o4;
}

extern "C" void kernel_launch(void* const* d_in, const int* in_sizes, int n_in,
                              void* d_out, int out_size, void* d_ws, size_t ws_size,
                              hipStream_t stream) {
  const float* x     = (const float*)d_in[0];
  const float* gamma = (const float*)d_in[1];
  const float* beta  = (const float*)d_in[2];
  const float* wq    = (const float*)d_in[3];
  const float* bq    = (const float*)d_in[4];
  const float* wk    = (const float*)d_in[5];
  const float* bk    = (const float*)d_in[6];
  const float* wv    = (const float*)d_in[7];
  const float* bv    = (const float*)d_in[8];
  const float* wo    = (const float*)d_in[9];
  const float* bo    = (const float*)d_in[10];
  float* out = (float*)d_out;

  unsigned char* w8 = (unsigned char*)d_ws;
  const size_t MB = 1024 * 1024;
  ushort_t* xn  = (ushort_t*)(w8 + 0 * MB);   // 8 MB; reused as attention output
  ushort_t* qb  = (ushort_t*)(w8 + 8 * MB);
  ushort_t* kb  = (ushort_t*)(w8 + 16 * MB);
  ushort_t* vt  = (ushort_t*)(w8 + 24 * MB);
  ushort_t* wtq = (ushort_t*)(w8 + 32 * MB);
  ushort_t* wtk = (ushort_t*)(w8 + 34 * MB);
  ushort_t* wtv = (ushort_t*)(w8 + 36 * MB);
  ushort_t* wto = (ushort_t*)(w8 + 38 * MB);
  float* Opart  = (float*)(w8 + 40 * MB);     // 32 MB (2 halves x 16 MB)
  float* lpart  = (float*)(w8 + 72 * MB);     // 512 KB
  ushort_t* ob  = xn;

  ln_kernel<<<dim3(NTOK), dim3(256), 0, stream>>>(x, gamma, beta, xn);
  wt_kernel<<<dim3(16, 16, 4), dim3(256), 0, stream>>>(wq, wk, wv, wo, wtq, wtk, wtv, wto);
  gemm_qkv<<<dim3(8, 32, 3), dim3(256), 0, stream>>>(xn, wtq, wtk, wtv, bq, bk, bv, qb, kb, vt);
  if (ws_size >= 73 * MB) {
    attn_kernel<1><<<dim3(SEQ / 64, 2 * NHEAD, 2), dim3(256), 0, stream>>>(
        qb, kb, vt, nullptr, Opart, lpart);
    combine_kernel<<<dim3(NTOK), dim3(256), 0, stream>>>(Opart, lpart, ob);
  } else {
    attn_kernel<0><<<dim3(SEQ / 64, 2 * NHEAD, 1), dim3(256), 0, stream>>>(
        qb, kb, vt, ob, nullptr, nullptr);
  }
  gemm_out<<<dim3(8, 32, 1), dim3(256), 0, stream>>>(ob, wto, bo, out);
}